// Round 1
// baseline (516.297 us; speedup 1.0000x reference)
//
#include <hip/hip_runtime.h>

// GraphAggregation: out[b][d] = mean over 196 nodes of in[b][n*4+d].
// Memory-bound: 411 MB read, 2 MB write. One wave per row; each node
// vector is a float4, so lane loads are 16B coalesced (1 KiB/wave/instr).

#define N_NODES 196
#define DIMS 4

__global__ __launch_bounds__(256) void graph_agg_kernel(
    const float* __restrict__ in, float* __restrict__ out, int B) {
    const int wave_in_block = threadIdx.x >> 6;   // 4 waves per block
    const int lane = threadIdx.x & 63;
    const int row = blockIdx.x * 4 + wave_in_block;
    if (row >= B) return;

    const float4* rowp = (const float4*)(in + (size_t)row * (N_NODES * DIMS));

    // 196 float4s per row = 64*3 + 4 remainder
    float4 v0 = rowp[lane];
    float4 v1 = rowp[lane + 64];
    float4 v2 = rowp[lane + 128];
    float4 acc;
    acc.x = v0.x + v1.x + v2.x;
    acc.y = v0.y + v1.y + v2.y;
    acc.z = v0.z + v1.z + v2.z;
    acc.w = v0.w + v1.w + v2.w;
    if (lane < 4) {
        float4 v3 = rowp[192 + lane];
        acc.x += v3.x; acc.y += v3.y; acc.z += v3.z; acc.w += v3.w;
    }

    // 64-lane butterfly reduction, component-wise
    #pragma unroll
    for (int off = 32; off >= 1; off >>= 1) {
        acc.x += __shfl_xor(acc.x, off);
        acc.y += __shfl_xor(acc.y, off);
        acc.z += __shfl_xor(acc.z, off);
        acc.w += __shfl_xor(acc.w, off);
    }

    if (lane == 0) {
        const float s = 1.0f / (float)N_NODES;
        float4 o;
        o.x = acc.x * s; o.y = acc.y * s; o.z = acc.z * s; o.w = acc.w * s;
        ((float4*)out)[row] = o;
    }
}

extern "C" void kernel_launch(void* const* d_in, const int* in_sizes, int n_in,
                              void* d_out, int out_size, void* d_ws, size_t ws_size,
                              hipStream_t stream) {
    const float* in = (const float*)d_in[0];
    float* out = (float*)d_out;
    const int B = in_sizes[0] / (N_NODES * DIMS);  // 131072
    const int rows_per_block = 4;                   // 4 waves of 64
    const int grid = (B + rows_per_block - 1) / rows_per_block;
    graph_agg_kernel<<<grid, 256, 0, stream>>>(in, out, B);
}

// Round 2
// 506.479 us; speedup vs baseline: 1.0194x; 1.0194x over previous
//
#include <hip/hip_runtime.h>

// GraphAggregation: out[b][d] = mean over 196 nodes of in[b][n*4+d].
// Memory-bound: 411 MB read / 2 MB write -> ~66 us floor at 6.3 TB/s.
//
// R1 structure: 16 lanes per row, 4 rows per wave, 16 rows per 256-block.
// Each lane locally accumulates 12 strided float4 nodes (12 independent
// global_load_dwordx4 in flight -> deep MLP), then a depth-4 __shfl_xor
// butterfly across the 16-lane group. R0's 1-wave-per-row had only 3 loads
// in flight per wave + a depth-6/24-op shuffle chain -> latency-bound at
// ~0.8 TB/s.

#define N_NODES 196
#define DIMS 4
#define ROW_F4 N_NODES  // 196 float4s per row

__global__ __launch_bounds__(256) void graph_agg_kernel(
    const float* __restrict__ in, float* __restrict__ out, int B) {
    const int wave = threadIdx.x >> 6;        // 4 waves / block
    const int lane = threadIdx.x & 63;
    const int group = lane >> 4;              // 4 row-groups / wave
    const int gl = lane & 15;                 // lane within group
    const int row = (blockIdx.x * 4 + wave) * 4 + group;  // 16 rows / block
    if (row >= B) return;

    const float4* __restrict__ rowp =
        (const float4*)(in + (size_t)row * (N_NODES * DIMS));

    // 196 = 12*16 + 4. Lane gl covers nodes gl, gl+16, ..., gl+176; lanes
    // 0..3 pick up nodes 192..195.
    float4 acc = make_float4(0.f, 0.f, 0.f, 0.f);
    #pragma unroll
    for (int i = 0; i < 12; ++i) {
        float4 v = rowp[gl + 16 * i];
        acc.x += v.x; acc.y += v.y; acc.z += v.z; acc.w += v.w;
    }
    if (gl < 4) {
        float4 v = rowp[192 + gl];
        acc.x += v.x; acc.y += v.y; acc.z += v.z; acc.w += v.w;
    }

    // Reduce across the 16-lane group (xor offsets 8,4,2,1 stay in-group).
    #pragma unroll
    for (int off = 8; off >= 1; off >>= 1) {
        acc.x += __shfl_xor(acc.x, off);
        acc.y += __shfl_xor(acc.y, off);
        acc.z += __shfl_xor(acc.z, off);
        acc.w += __shfl_xor(acc.w, off);
    }

    if (gl == 0) {
        const float s = 1.0f / (float)N_NODES;
        float4 o;
        o.x = acc.x * s; o.y = acc.y * s; o.z = acc.z * s; o.w = acc.w * s;
        ((float4*)out)[row] = o;
    }
}

extern "C" void kernel_launch(void* const* d_in, const int* in_sizes, int n_in,
                              void* d_out, int out_size, void* d_ws, size_t ws_size,
                              hipStream_t stream) {
    const float* in = (const float*)d_in[0];
    float* out = (float*)d_out;
    const int B = in_sizes[0] / (N_NODES * DIMS);  // 131072
    const int rows_per_block = 16;                  // 4 waves x 4 rows
    const int grid = (B + rows_per_block - 1) / rows_per_block;
    graph_agg_kernel<<<grid, 256, 0, stream>>>(in, out, B);
}

// Round 4
// 500.081 us; speedup vs baseline: 1.0324x; 1.0128x over previous
//
#include <hip/hip_runtime.h>

// GraphAggregation: out[b][d] = mean over 196 nodes of in[b][n*4+d].
// Memory-bound: 411 MB read / 2 MB write -> ~66 us kernel floor at 6.3 TB/s.
// Measured dur_us (~506) is dominated by harness re-poison fills (2 x 1.6 GB
// at ~253 us each, visible as the top rocprof dispatches); our kernel is
// < 252 us and estimated ~60-75 us.
//
// R3 = R2 with the nontemporal builtins fed Clang native vector types
// (ext_vector_type(4) float) instead of HIP_vector_type float4, which the
// builtin rejects. Structure: 4 lanes per row, 49 float4 loads per lane
// (196 = 4*49, no tail divergence), depth-2 shuffle reduction, nontemporal
// loads (input streams once, 411 MB > 256 MB L3 -> no reuse).

#define N_NODES 196
#define DIMS 4

typedef float vfloat4 __attribute__((ext_vector_type(4)));

__global__ __launch_bounds__(256) void graph_agg_kernel(
    const float* __restrict__ in, float* __restrict__ out, int B) {
    const int lane = threadIdx.x & 63;
    const int gl = lane & 3;                   // lane within 4-lane row-group
    const int group = threadIdx.x >> 2;        // 64 row-groups per 256-block
    const int row = blockIdx.x * 64 + group;
    if (row >= B) return;

    const vfloat4* __restrict__ rowp =
        (const vfloat4*)(in + (size_t)row * (N_NODES * DIMS));

    // Lane gl covers nodes gl, gl+4, ..., gl+192 (49 nodes, no remainder).
    vfloat4 acc = (vfloat4)(0.f);
    #pragma unroll
    for (int i = 0; i < 49; ++i) {
        vfloat4 v = __builtin_nontemporal_load(&rowp[gl + 4 * i]);
        acc += v;
    }

    // Reduce across the 4-lane group (xor offsets 2,1 stay in-group).
    #pragma unroll
    for (int off = 2; off >= 1; off >>= 1) {
        acc.x += __shfl_xor(acc.x, off);
        acc.y += __shfl_xor(acc.y, off);
        acc.z += __shfl_xor(acc.z, off);
        acc.w += __shfl_xor(acc.w, off);
    }

    if (gl == 0) {
        const float s = 1.0f / (float)N_NODES;
        vfloat4 o = acc * s;
        __builtin_nontemporal_store(o, &((vfloat4*)out)[row]);
    }
}

extern "C" void kernel_launch(void* const* d_in, const int* in_sizes, int n_in,
                              void* d_out, int out_size, void* d_ws, size_t ws_size,
                              hipStream_t stream) {
    const float* in = (const float*)d_in[0];
    float* out = (float*)d_out;
    const int B = in_sizes[0] / (N_NODES * DIMS);  // 131072
    const int rows_per_block = 64;                  // 4 waves x 16 rows each
    const int grid = (B + rows_per_block - 1) / rows_per_block;
    graph_agg_kernel<<<grid, 256, 0, stream>>>(in, out, B);
}